// Round 3
// 691.991 us; speedup vs baseline: 1.1120x; 1.1120x over previous
//
#include <hip/hip_runtime.h>

#define S_LEN 1024
#define B_SZ 2
#define H_DIM 4096
#define NHEADS 32
#define KVHEADS 8
#define HDIM 128

typedef _Float16 half8 __attribute__((ext_vector_type(8)));
typedef float f4 __attribute__((ext_vector_type(4)));
typedef unsigned short ushort_t;

static __device__ __forceinline__ ushort_t f2h(float x) {
  _Float16 h = (_Float16)x;
  return __builtin_bit_cast(unsigned short, h);
}
static __device__ __forceinline__ float h2f(ushort_t u) {
  return (float)__builtin_bit_cast(_Float16, u);
}

// async global->LDS, 16B per lane. LDS dest must be wave-uniform base + lane*16.
static __device__ __forceinline__ void gl2lds16(const void* g, void* l) {
  __builtin_amdgcn_global_load_lds(
      (const __attribute__((address_space(1))) unsigned int*)(unsigned long long)(uintptr_t)g,
      (__attribute__((address_space(3))) unsigned int*)(unsigned int)(uintptr_t)l,
      16, 0, 0);
}

#define WAITVM4 asm volatile("s_waitcnt vmcnt(4)" ::: "memory")
#define WAITVM0 asm volatile("s_waitcnt vmcnt(0)" ::: "memory")
#define BAR() __builtin_amdgcn_s_barrier()
#define SCHED_FENCE() __builtin_amdgcn_sched_barrier(0)

// ---------------- fp32 -> fp16 conversion --------------------------------
__global__ __launch_bounds__(256) void cvt16(const float* __restrict__ x,
                                             ushort_t* __restrict__ h, int n4) {
  int i = blockIdx.x * 256 + threadIdx.x;
  if (i >= n4) return;
  float4 v = ((const float4*)x)[i];
  uint2 hp;
  hp.x = (unsigned)f2h(v.x) | ((unsigned)f2h(v.y) << 16);
  hp.y = (unsigned)f2h(v.z) | ((unsigned)f2h(v.w) << 16);
  ((uint2*)h)[i] = hp;
}

// ---------------- 256x256 pipelined GEMM core (64 KiB static LDS) ---------
// Tile 256x256, BK=32, 512 threads = 8 waves (2M x 4N; per-wave 128x64 out,
// rows interleaved: row = wy*16 + mi*32 + ln).
// LDS: A[2buf][256][32] fp16 (32 KiB) then B likewise (32 KiB). Per K-tile:
//   stage(t+1) -> buf^1 ; s_waitcnt vmcnt(4) (stage(t) landed, stage(t+1)
//   still in flight) ; s_barrier ; sched_fence ; ds_read ; 32 MFMA ; barrier.
// Counted wait: loads stay outstanding across the barrier (T4); drain to 0
// only at the last tile. Swizzle: 16B chunk c ^= (row&3) applied on the
// global SOURCE (linear global_load_lds dest, rule 21) and on ds_read addr.

static __device__ __forceinline__ void stage_tile(const ushort_t* __restrict__ src,
                                                  char* ldsBase, int tid) {
  const int r = tid >> 2;                     // 0..127
  const int c = ((tid & 3) ^ (r & 3)) << 3;   // pre-swizzled 16B chunk (elems)
  gl2lds16(src + (size_t)r * 4096 + c, ldsBase + tid * 16);
  gl2lds16(src + (size_t)(r + 128) * 4096 + c, ldsBase + 8192 + tid * 16);
}

static __device__ __forceinline__ void gemm256_core(
    const ushort_t* __restrict__ Ahg, const ushort_t* __restrict__ Bhg,
    int m0, int n0, int kbase, int NT, char* lds, f4 (&acc)[8][4]) {
  const int tid = threadIdx.x;
  const int wid = tid >> 6;
  const int lane = tid & 63;
  const int ln = lane & 15;
  const int quad = lane >> 4;
  const int wy = wid >> 2, wx = wid & 3;
  const int chunk = (quad ^ (ln & 3)) << 4;   // swizzled chunk byte offset

  const ushort_t* Abase = Ahg + (size_t)m0 * 4096 + kbase;
  const ushort_t* Bbase = Bhg + (size_t)n0 * 4096 + kbase;

  // prologue: stage tile 0 (4 block-wide load instrs, 2 per matrix)
  stage_tile(Abase, lds, tid);
  stage_tile(Bbase, lds + 32768, tid);

  int cur = 0;
  for (int t = 0; t < NT; ++t) {
    const bool st = (t + 1 < NT);
    char* aCur = lds + cur * 16384;
    char* bCur = lds + 32768 + cur * 16384;
    if (st) {
      // issue next-tile loads; they stay in flight through this tile's MFMA
      stage_tile(Abase + (t + 1) * 32, lds + (cur ^ 1) * 16384, tid);
      stage_tile(Bbase + (t + 1) * 32, lds + 32768 + (cur ^ 1) * 16384, tid);
      WAITVM4;   // all but the 4 newest (= stage(t+1)) landed => stage(t) done
    } else {
      WAITVM0;   // last tile: drain
    }
    BAR();        // every wave confirmed ITS stage(t) portion -> tile ready
    SCHED_FENCE();  // pin ds_reads below the barrier

    half8 Af[8], Bf[4];
#pragma unroll
    for (int mi = 0; mi < 8; ++mi) {
      int row = wy * 16 + mi * 32 + ln;
      Af[mi] = *(const half8*)(aCur + row * 64 + chunk);
    }
#pragma unroll
    for (int ni = 0; ni < 4; ++ni) {
      int row = wx * 16 + ni * 64 + ln;
      Bf[ni] = *(const half8*)(bCur + row * 64 + chunk);
    }
    __builtin_amdgcn_s_setprio(1);
#pragma unroll
    for (int mi = 0; mi < 8; ++mi)
#pragma unroll
      for (int ni = 0; ni < 4; ++ni)
        acc[mi][ni] = __builtin_amdgcn_mfma_f32_16x16x32_f16(Af[mi], Bf[ni], acc[mi][ni], 0, 0, 0);
    __builtin_amdgcn_s_setprio(0);
    BAR();        // all waves done reading buf[cur] before it is re-staged
    cur ^= 1;
  }
}

// ---------------- fused QKV GEMM: (2048x4096) @ (6144x4096)^T -------------
// cols 0..4095 -> Qout fp16 (2048x4096); cols 4096..6143 -> KVout fp32
__global__ __launch_bounds__(512, 2) void gemm_qkv(const ushort_t* __restrict__ Ahg,
                                                   const ushort_t* __restrict__ Bhg,
                                                   ushort_t* __restrict__ Qout,
                                                   float* __restrict__ KVout) {
  __shared__ __align__(16) char lds[65536];
  f4 acc[8][4];
#pragma unroll
  for (int i = 0; i < 8; ++i)
#pragma unroll
    for (int j = 0; j < 4; ++j) acc[i][j] = (f4){0.f, 0.f, 0.f, 0.f};
  const int m0 = blockIdx.y * 256, n0 = blockIdx.x * 256;
  gemm256_core(Ahg, Bhg, m0, n0, 0, 128, lds, acc);

  const int tid = threadIdx.x;
  const int wid = tid >> 6, lane = tid & 63, ln = lane & 15, quad = lane >> 4;
  const int wy = wid >> 2, wx = wid & 3;
  if (n0 < 4096) {
#pragma unroll
    for (int mi = 0; mi < 8; ++mi) {
      int row = m0 + wy * 16 + mi * 32 + quad * 4;
#pragma unroll
      for (int ni = 0; ni < 4; ++ni) {
        int col = n0 + wx * 16 + ni * 64 + ln;
        ushort_t* cp = Qout + (size_t)row * 4096 + col;
#pragma unroll
        for (int r = 0; r < 4; ++r) cp[(size_t)r * 4096] = f2h(acc[mi][ni][r]);
      }
    }
  } else {
#pragma unroll
    for (int mi = 0; mi < 8; ++mi) {
      int row = m0 + wy * 16 + mi * 32 + quad * 4;
#pragma unroll
      for (int ni = 0; ni < 4; ++ni) {
        int col = n0 - 4096 + wx * 16 + ni * 64 + ln;
        float* cp = KVout + (size_t)row * 2048 + col;
#pragma unroll
        for (int r = 0; r < 4; ++r) cp[(size_t)r * 2048] = acc[mi][ni][r];
      }
    }
  }
}

// ---------------- O GEMM, split-K=2: (2048x4096) @ (4096x4096)^T ----------
__global__ __launch_bounds__(512, 2) void gemm_o(const ushort_t* __restrict__ Ahg,
                                                 const ushort_t* __restrict__ Bhg,
                                                 float* __restrict__ C0,
                                                 float* __restrict__ C1) {
  __shared__ __align__(16) char lds[65536];
  f4 acc[8][4];
#pragma unroll
  for (int i = 0; i < 8; ++i)
#pragma unroll
    for (int j = 0; j < 4; ++j) acc[i][j] = (f4){0.f, 0.f, 0.f, 0.f};
  const int m0 = blockIdx.y * 256, n0 = blockIdx.x * 256;
  const int kz = blockIdx.z * 2048;
  gemm256_core(Ahg, Bhg, m0, n0, kz, 64, lds, acc);

  const int tid = threadIdx.x;
  const int wid = tid >> 6, lane = tid & 63, ln = lane & 15, quad = lane >> 4;
  const int wy = wid >> 2, wx = wid & 3;
  float* Cp = blockIdx.z ? C1 : C0;
#pragma unroll
  for (int mi = 0; mi < 8; ++mi) {
    int row = m0 + wy * 16 + mi * 32 + quad * 4;
#pragma unroll
    for (int ni = 0; ni < 4; ++ni) {
      int col = n0 + wx * 16 + ni * 64 + ln;
      float* cp = Cp + (size_t)row * 4096 + col;
#pragma unroll
      for (int r = 0; r < 4; ++r) cp[(size_t)r * 4096] = acc[mi][ni][r];
    }
  }
}

__global__ __launch_bounds__(256) void reduce2(float* __restrict__ out,
                                               const float* __restrict__ p1, int n4) {
  int i = blockIdx.x * 256 + threadIdx.x;
  if (i >= n4) return;
  float4 a = ((const float4*)out)[i];
  float4 b = ((const float4*)p1)[i];
  a.x += b.x; a.y += b.y; a.z += b.z; a.w += b.w;
  ((float4*)out)[i] = a;
}

// ---------------- K fake-quant: per-column stats over 2048 rows -----------
__global__ __launch_bounds__(256) void kquant(float* __restrict__ KV) {
  __shared__ float s[2048];
  __shared__ float red[256];
  const int c = blockIdx.x, tid = threadIdx.x;
  float x[8];
#pragma unroll
  for (int i = 0; i < 8; i++) {
    x[i] = KV[(size_t)(tid + i * 256) * 2048 + c];
    s[tid + i * 256] = x[i];
  }
  __syncthreads();
  for (int k = 2; k <= 2048; k <<= 1)
    for (int j = k >> 1; j > 0; j >>= 1) {
      for (int i = tid; i < 2048; i += 256) {
        int l = i ^ j;
        if (l > i) {
          float a = s[i], b2 = s[l];
          bool up = ((i & k) == 0);
          if ((a > b2) == up) { s[i] = b2; s[l] = a; }
        }
      }
      __syncthreads();
    }
  float lower = s[1]    + 0.0235f * (s[2]    - s[1]);
  float upper = s[2045] + 0.9765f * (s[2046] - s[2045]);
  float med   = s[1023];
  float mx = -__builtin_inff(), mn = __builtin_inff();
#pragma unroll
  for (int i = 0; i < 8; i++) {
    bool m = (x[i] <= lower) | (x[i] >= upper);
    float t = m ? med : x[i];
    mx = fmaxf(mx, t);
    mn = fminf(mn, t);
  }
  __syncthreads();
  red[tid] = mx; __syncthreads();
  for (int off = 128; off > 0; off >>= 1) {
    if (tid < off) red[tid] = fmaxf(red[tid], red[tid + off]);
    __syncthreads();
  }
  mx = red[0]; __syncthreads();
  red[tid] = mn; __syncthreads();
  for (int off = 128; off > 0; off >>= 1) {
    if (tid < off) red[tid] = fminf(red[tid], red[tid + off]);
    __syncthreads();
  }
  mn = red[0];
  float qx = 15.0f / (mx - mn);
  float offv = mn * qx;
#pragma unroll
  for (int i = 0; i < 8; i++) {
    bool m = (x[i] <= lower) | (x[i] >= upper);
    float inp = m ? 0.f : x[i];
    float q = rintf(qx * inp - offv);
    q = fminf(fmaxf(q, 0.f), 15.f);
    float deq = (q + offv) / qx;
    float o = m ? x[i] : deq;
    if (!__builtin_isfinite(o)) o = 0.f;
    KV[(size_t)(tid + i * 256) * 2048 + c] = o;
  }
}

// ---------------- V fake-quant: per-row stats; writes fp16 rows -----------
__global__ __launch_bounds__(256) void vquant(const float* __restrict__ KV,
                                              ushort_t* __restrict__ vrow) {
  __shared__ float s[1024];
  __shared__ float red[256];
  const int rrow = blockIdx.x, tid = threadIdx.x;
  float x[4];
#pragma unroll
  for (int i = 0; i < 4; i++) {
    x[i] = KV[(size_t)rrow * 2048 + 1024 + tid + i * 256];
    s[tid + i * 256] = x[i];
  }
  __syncthreads();
  for (int k = 2; k <= 1024; k <<= 1)
    for (int j = k >> 1; j > 0; j >>= 1) {
      for (int i = tid; i < 1024; i += 256) {
        int l = i ^ j;
        if (l > i) {
          float a = s[i], b2 = s[l];
          bool up = ((i & k) == 0);
          if ((a > b2) == up) { s[i] = b2; s[l] = a; }
        }
      }
      __syncthreads();
    }
  float lower = s[0]    + 0.5115f * (s[1]    - s[0]);
  float upper = s[1022] + 0.4885f * (s[1023] - s[1022]);
  float med   = s[511];
  float mx = -__builtin_inff(), mn = __builtin_inff();
#pragma unroll
  for (int i = 0; i < 4; i++) {
    bool m = (x[i] <= lower) | (x[i] >= upper);
    float t = m ? med : x[i];
    mx = fmaxf(mx, t);
    mn = fminf(mn, t);
  }
  __syncthreads();
  red[tid] = mx; __syncthreads();
  for (int off = 128; off > 0; off >>= 1) {
    if (tid < off) red[tid] = fmaxf(red[tid], red[tid + off]);
    __syncthreads();
  }
  mx = red[0]; __syncthreads();
  red[tid] = mn; __syncthreads();
  for (int off = 128; off > 0; off >>= 1) {
    if (tid < off) red[tid] = fminf(red[tid], red[tid + off]);
    __syncthreads();
  }
  mn = red[0];
  float qx = 15.0f / (mx - mn);
  float offv = mn * qx;
#pragma unroll
  for (int i = 0; i < 4; i++) {
    bool m = (x[i] <= lower) | (x[i] >= upper);
    float inp = m ? 0.f : x[i];
    float q = rintf(qx * inp - offv);
    q = fminf(fmaxf(q, 0.f), 15.f);
    float deq = (q + offv) / qx;
    float o = m ? x[i] : deq;
    if (!__builtin_isfinite(o)) o = 0.f;
    vrow[(size_t)rrow * 1024 + tid + i * 256] = f2h(o);
  }
}

// ---------------- V transpose: vrow(2048,1024) -> vb(B,KVH,128,1024) ------
__global__ __launch_bounds__(256) void vtrans(const ushort_t* __restrict__ vrow,
                                              ushort_t* __restrict__ vb) {
  __shared__ ushort_t T[64 * 65];
  const int c0 = blockIdx.x * 64, r0 = blockIdx.y * 64;
  const int b = r0 >> 10, sbase = r0 & 1023;
#pragma unroll
  for (int i = 0; i < 2; i++) {
    int idx = threadIdx.x + i * 256;
    int r = idx >> 3, c8 = (idx & 7) * 8;
    uint4 v = *(const uint4*)(vrow + (size_t)(r0 + r) * 1024 + c0 + c8);
    const ushort_t* p = (const ushort_t*)&v;
#pragma unroll
    for (int j = 0; j < 8; j++) T[r * 65 + c8 + j] = p[j];
  }
  __syncthreads();
#pragma unroll
  for (int i = 0; i < 2; i++) {
    int idx = threadIdx.x + i * 256;
    int c = idx >> 3, s8 = (idx & 7) * 8;
    ushort_t tmp[8];
#pragma unroll
    for (int j = 0; j < 8; j++) tmp[j] = T[(s8 + j) * 65 + c];
    int gc = c0 + c;  // h*128 + d
    size_t oa = ((size_t)(b * KVHEADS + (gc >> 7)) * HDIM + (gc & 127)) * S_LEN + sbase + s8;
    *(uint4*)(vb + oa) = *(const uint4*)tmp;
  }
}

// ---------------- RoPE Q: (B,S,NH*D) fp16 -> (B,NH,S,D) fp16, prescaled ---
__global__ __launch_bounds__(256) void rope_q(const ushort_t* __restrict__ Q,
                                              const int* __restrict__ pos,
                                              ushort_t* __restrict__ qb) {
  int t = blockIdx.x * 256 + threadIdx.x;
  int i = t & 63;
  int h = (t >> 6) & 31;
  int s = (t >> 11) & 1023;
  int b = t >> 21;
  int p = pos[b * S_LEN + s];
  float inv = expf(-9.210340371976184f * ((float)i * (1.0f / 64.0f)));
  float ang = (float)p * inv;
  float sn, cs;
  sincosf(ang, &sn, &cs);
  size_t base = ((size_t)(b * S_LEN + s)) * H_DIM + h * HDIM + i;
  float x1 = h2f(Q[base]), x2 = h2f(Q[base + 64]);
  const float sc = 0.08838834764831845f;  // 1/sqrt(128)
  size_t ob = (((size_t)(b * NHEADS + h)) * S_LEN + s) * HDIM + i;
  qb[ob]      = f2h((x1 * cs - x2 * sn) * sc);
  qb[ob + 64] = f2h((x2 * cs + x1 * sn) * sc);
}

// ---------------- RoPE K from combined KV fp32 ----------------------------
__global__ __launch_bounds__(256) void rope_k(const float* __restrict__ KV,
                                              const int* __restrict__ pos,
                                              ushort_t* __restrict__ kb) {
  int t = blockIdx.x * 256 + threadIdx.x;
  int i = t & 63;
  int h = (t >> 6) & 7;
  int s = (t >> 9) & 1023;
  int b = t >> 19;
  int p = pos[b * S_LEN + s];
  float inv = expf(-9.210340371976184f * ((float)i * (1.0f / 64.0f)));
  float ang = (float)p * inv;
  float sn, cs;
  sincosf(ang, &sn, &cs);
  size_t base = ((size_t)(b * S_LEN + s)) * 2048 + h * HDIM + i;
  float k1 = KV[base], k2 = KV[base + 64];
  size_t ob = (((size_t)(b * KVHEADS + h)) * S_LEN + s) * HDIM + i;
  kb[ob]      = f2h(k1 * cs - k2 * sn);
  kb[ob + 64] = f2h(k2 * cs + k1 * sn);
}

// ---------------- Flash attention (causal, GQA), 128-query tiles ----------
__global__ __launch_bounds__(256) void attn_fwd(const ushort_t* __restrict__ qb,
                                                const ushort_t* __restrict__ kb,
                                                const ushort_t* __restrict__ vb,
                                                ushort_t* __restrict__ ob) {
  __shared__ short Ks[64 * 136];    // keys row-major [k][d], pad 8
  __shared__ short Vs[128 * 72];    // V^T [d][s], pad 8
  __shared__ short Ps[4 * 32 * 72]; // per-wave P [q][k], pad 8
  const int tid = threadIdx.x;
  const int wid = tid >> 6;
  const int lane = tid & 63;
  const int ln = lane & 15;
  const int quad = lane >> 4;
  const int q0 = blockIdx.x * 128;
  const int bh = blockIdx.y;
  const int b = bh >> 5, h = bh & 31, hk = h >> 2;

  half8 aq[2][4];
#pragma unroll
  for (int mi = 0; mi < 2; mi++) {
    const ushort_t* qrow =
        qb + (((size_t)(b * NHEADS + h)) * S_LEN + q0 + wid * 32 + mi * 16 + ln) * HDIM;
#pragma unroll
    for (int ks = 0; ks < 4; ks++) aq[mi][ks] = *(const half8*)(qrow + ks * 32 + quad * 8);
  }

  f4 accO[2][8];
#pragma unroll
  for (int mi = 0; mi < 2; mi++)
#pragma unroll
    for (int i = 0; i < 8; i++) accO[mi][i] = (f4){0.f, 0.f, 0.f, 0.f};
  float mr[2][4], lr[2][4];
#pragma unroll
  for (int mi = 0; mi < 2; mi++)
#pragma unroll
    for (int r = 0; r < 4; r++) { mr[mi][r] = -__builtin_inff(); lr[mi][r] = 0.f; }

  const ushort_t* kbp = kb + ((size_t)(b * KVHEADS + hk)) * S_LEN * HDIM;
  const ushort_t* vbp = vb + ((size_t)(b * KVHEADS + hk)) * HDIM * S_LEN;

  const int ktiles = 2 * blockIdx.x + 2;
  for (int kt = 0; kt < ktiles; kt++) {
    const int k0 = kt * 64;
    __syncthreads();
#pragma unroll
    for (int cc = 0; cc < 4; cc++) {
      int idx = tid + cc * 256;
      int r = idx >> 4, c8 = idx & 15;
      *(uint4*)&Ks[r * 136 + c8 * 8] = *(const uint4*)(kbp + (size_t)(k0 + r) * HDIM + c8 * 8);
      int d = idx >> 3, s8 = idx & 7;
      *(uint4*)&Vs[d * 72 + s8 * 8] = *(const uint4*)(vbp + (size_t)d * S_LEN + k0 + s8 * 8);
    }
    __syncthreads();

    if (q0 + wid * 32 + 31 < k0) continue;  // fully masked wave (uniform branch)

    f4 sc[2][4];
#pragma unroll
    for (int mi = 0; mi < 2; mi++)
#pragma unroll
      for (int nt = 0; nt < 4; nt++) sc[mi][nt] = (f4){0.f, 0.f, 0.f, 0.f};
#pragma unroll
    for (int nt = 0; nt < 4; nt++) {
      half8 bk[4];
#pragma unroll
      for (int ks = 0; ks < 4; ks++)
        bk[ks] = *(const half8*)&Ks[(nt * 16 + ln) * 136 + ks * 32 + quad * 8];
#pragma unroll
      for (int mi = 0; mi < 2; mi++)
#pragma unroll
        for (int ks = 0; ks < 4; ks++)
          sc[mi][nt] = __builtin_amdgcn_mfma_f32_16x16x32_f16(aq[mi][ks], bk[ks], sc[mi][nt], 0, 0, 0);
    }
#pragma unroll
    for (int mi = 0; mi < 2; mi++)
#pragma unroll
      for (int r = 0; r < 4; r++) {
        int mq = q0 + wid * 32 + mi * 16 + quad * 4 + r;
#pragma unroll
        for (int nt = 0; nt < 4; nt++) {
          int nk = k0 + nt * 16 + ln;
          if (nk > mq) sc[mi][nt][r] = -1e30f;
        }
      }
    float al[2][4];
#pragma unroll
    for (int mi = 0; mi < 2; mi++)
#pragma unroll
      for (int r = 0; r < 4; r++) {
        float tm = fmaxf(fmaxf(sc[mi][0][r], sc[mi][1][r]), fmaxf(sc[mi][2][r], sc[mi][3][r]));
        tm = fmaxf(tm, __shfl_xor(tm, 1));
        tm = fmaxf(tm, __shfl_xor(tm, 2));
        tm = fmaxf(tm, __shfl_xor(tm, 4));
        tm = fmaxf(tm, __shfl_xor(tm, 8));
        float mnew = fmaxf(mr[mi][r], tm);
        al[mi][r] = __expf(mr[mi][r] - mnew);
        mr[mi][r] = mnew;
        float ls = 0.f;
#pragma unroll
        for (int nt = 0; nt < 4; nt++) {
          float pp = __expf(sc[mi][nt][r] - mnew);
          sc[mi][nt][r] = pp;
          ls += pp;
        }
        ls += __shfl_xor(ls, 1);
        ls += __shfl_xor(ls, 2);
        ls += __shfl_xor(ls, 4);
        ls += __shfl_xor(ls, 8);
        lr[mi][r] = lr[mi][r] * al[mi][r] + ls;
      }
#pragma unroll
    for (int mi = 0; mi < 2; mi++)
#pragma unroll
      for (int dt = 0; dt < 8; dt++)
#pragma unroll
        for (int r = 0; r < 4; r++) accO[mi][dt][r] *= al[mi][r];
#pragma unroll
    for (int mi = 0; mi < 2; mi++)
#pragma unroll
      for (int r = 0; r < 4; r++)
#pragma unroll
        for (int nt = 0; nt < 4; nt++)
          Ps[wid * 2304 + (mi * 16 + quad * 4 + r) * 72 + nt * 16 + ln] =
              (short)f2h(sc[mi][nt][r]);
    half8 ap[2][2];
#pragma unroll
    for (int mi = 0; mi < 2; mi++)
#pragma unroll
      for (int k2 = 0; k2 < 2; k2++)
        ap[mi][k2] = *(const half8*)&Ps[wid * 2304 + (mi * 16 + ln) * 72 + k2 * 32 + quad * 8];
#pragma unroll
    for (int dt = 0; dt < 8; dt++)
#pragma unroll
      for (int k2 = 0; k2 < 2; k2++) {
        half8 bv = *(const half8*)&Vs[(dt * 16 + ln) * 72 + k2 * 32 + quad * 8];
#pragma unroll
        for (int mi = 0; mi < 2; mi++)
          accO[mi][dt] = __builtin_amdgcn_mfma_f32_16x16x32_f16(ap[mi][k2], bv, accO[mi][dt], 0, 0, 0);
      }
  }
#pragma unroll
  for (int mi = 0; mi < 2; mi++)
#pragma unroll
    for (int r = 0; r < 4; r++) {
      float invl = 1.0f / lr[mi][r];
      int so = q0 + wid * 32 + mi * 16 + quad * 4 + r;
      size_t obase = ((size_t)(b * S_LEN + so)) * H_DIM + h * HDIM;
#pragma unroll
      for (int dt = 0; dt < 8; dt++)
        ob[obase + dt * 16 + ln] = f2h(accO[mi][dt][r] * invl);
    }
}

extern "C" void kernel_launch(void* const* d_in, const int* in_sizes, int n_in,
                              void* d_out, int out_size, void* d_ws, size_t ws_size,
                              hipStream_t stream) {
  const float* hidden = (const float*)d_in[0];
  const float* Wq = (const float*)d_in[1];
  const float* Wk = (const float*)d_in[2];
  const float* Wv = (const float*)d_in[3];
  const float* Wo = (const float*)d_in[4];
  const int* pos = (const int*)d_in[5];
  float* outp = (float*)d_out;

  // workspace layout (~113 MB) with lifetime-based reuse
  char* ws = (char*)d_ws;
  ushort_t* Wall = (ushort_t*)ws; ws += (size_t)6144 * 4096 * 2;  // [Wq;Wk;Wv] fp16; later Wo fp16 + qb
  ushort_t* hh   = (ushort_t*)ws; ws += (size_t)2048 * 4096 * 2;  // hidden fp16; later ab
  ushort_t* Qf16 = (ushort_t*)ws; ws += (size_t)2048 * 4096 * 2;  // Q proj out; later P1 (w/ KVf)
  float*    KVf  = (float*)ws;    ws += (size_t)2048 * 2048 * 4;  // KV proj out fp32
  ushort_t* vrow = (ushort_t*)ws; ws += (size_t)2048 * 1024 * 2;  // quantized V rows fp16
  ushort_t* kb   = (ushort_t*)ws; ws += (size_t)2048 * 1024 * 2;  // (B,KVH,S,D) fp16
  ushort_t* vb   = (ushort_t*)ws;                                 // (B,KVH,D,S) fp16

  ushort_t* Woh = Wall;                               // Wo fp16 (after QKV GEMM)
  ushort_t* qb  = Wall + (size_t)4096 * 4096;         // (B,NH,S,D), overlays Wk/Wv fp16
  ushort_t* ab  = hh;                                 // attn out (B,S,NH*D)
  float*    P1  = (float*)Qf16;                       // split-K partial, overlays Qf16+KVf

  // conversions to fp16
  cvt16<<<8192, 256, 0, stream>>>(hidden, hh, 2048 * 4096 / 4);
  cvt16<<<16384, 256, 0, stream>>>(Wq, Wall, 4096 * 4096 / 4);
  cvt16<<<4096, 256, 0, stream>>>(Wk, Wall + (size_t)4096 * 4096, 1024 * 4096 / 4);
  cvt16<<<4096, 256, 0, stream>>>(Wv, Wall + (size_t)5120 * 4096, 1024 * 4096 / 4);

  // fused QKV projection (256^2 tiles, 24x8 grid, 512 threads, 64 KiB LDS)
  gemm_qkv<<<dim3(24, 8), 512, 0, stream>>>(hh, Wall, Qf16, KVf);

  // fake-quant (exact order statistics)
  kquant<<<1024, 256, 0, stream>>>(KVf);
  vquant<<<2048, 256, 0, stream>>>(KVf, vrow);
  vtrans<<<dim3(16, 32), 256, 0, stream>>>(vrow, vb);

  // RoPE + layout (qb overlays dead Wk/Wv region)
  rope_q<<<16384, 256, 0, stream>>>(Qf16, pos, qb);
  rope_k<<<4096, 256, 0, stream>>>(KVf, pos, kb);

  // Wo conversion into Wall head (Wq fp16 dead)
  cvt16<<<16384, 256, 0, stream>>>(Wo, Woh, 4096 * 4096 / 4);

  // attention
  attn_fwd<<<dim3(8, 64), 256, 0, stream>>>(qb, kb, vb, ab);

  // output projection, split-K=2 (z=0 -> outp, z=1 -> P1), then reduce
  gemm_o<<<dim3(16, 8, 2), 512, 0, stream>>>(ab, Woh, outp, P1);
  reduce2<<<8192, 256, 0, stream>>>(outp, P1, 2048 * 4096 / 4);
}

// Round 4
// 675.179 us; speedup vs baseline: 1.1397x; 1.0249x over previous
//
#include <hip/hip_runtime.h>

#define S_LEN 1024
#define B_SZ 2
#define H_DIM 4096
#define NHEADS 32
#define KVHEADS 8
#define HDIM 128

typedef _Float16 half8 __attribute__((ext_vector_type(8)));
typedef float f4 __attribute__((ext_vector_type(4)));
typedef unsigned short ushort_t;

static __device__ __forceinline__ ushort_t f2h(float x) {
  _Float16 h = (_Float16)x;
  return __builtin_bit_cast(unsigned short, h);
}
static __device__ __forceinline__ float h2f(ushort_t u) {
  return (float)__builtin_bit_cast(_Float16, u);
}

// async global->LDS, 16B per lane. LDS dest must be wave-uniform base + lane*16.
static __device__ __forceinline__ void gl2lds16(const void* g, void* l) {
  __builtin_amdgcn_global_load_lds(
      (const __attribute__((address_space(1))) unsigned int*)(unsigned long long)(uintptr_t)g,
      (__attribute__((address_space(3))) unsigned int*)(unsigned int)(uintptr_t)l,
      16, 0, 0);
}

#define WAITVM4 asm volatile("s_waitcnt vmcnt(4)" ::: "memory")
#define WAITVM0 asm volatile("s_waitcnt vmcnt(0)" ::: "memory")
#define BAR() __builtin_amdgcn_s_barrier()
#define SCHED_FENCE() __builtin_amdgcn_sched_barrier(0)

// ---------------- fp32 -> fp16 conversion --------------------------------
__global__ __launch_bounds__(256) void cvt16(const float* __restrict__ x,
                                             ushort_t* __restrict__ h, int n4) {
  int i = blockIdx.x * 256 + threadIdx.x;
  if (i >= n4) return;
  float4 v = ((const float4*)x)[i];
  uint2 hp;
  hp.x = (unsigned)f2h(v.x) | ((unsigned)f2h(v.y) << 16);
  hp.y = (unsigned)f2h(v.z) | ((unsigned)f2h(v.w) << 16);
  ((uint2*)h)[i] = hp;
}

// ---------------- 256x256 pipelined GEMM core (64 KiB static LDS) ---------
// Tile 256x256, BK=32, 512 threads = 8 waves (2M x 4N; per-wave 128x64 out,
// rows interleaved: row = wy*16 + mi*32 + ln).
// LDS: A[2buf][256][32] fp16 (32 KiB) then B likewise (32 KiB). Per K-tile:
//   stage(t+1) -> buf^1 ; s_waitcnt vmcnt(4) (stage(t) landed, stage(t+1)
//   still in flight) ; s_barrier ; sched_fence ; ds_read ; 32 MFMA ; barrier.
// Counted wait: loads stay outstanding across the barrier (T4); drain to 0
// only at the last tile.
// Swizzle (bank-conflict fix, r3 post-mortem): a row's 64B K-slice is 4
// 16B slots; slot s of row r holds global chunk s ^ ((r>>1)&3). Using
// (r>>1) — NOT (r&3), whose bit0 aliases the lane parity bit — makes the
// 16 lanes of a quad-group cover all 8 (parity,slot) combos 2x => 2-way
// (free, m136). Write side pre-swizzles the GLOBAL source (linear
// global_load_lds dest, rule 21); read side applies the same involution.

static __device__ __forceinline__ void stage_tile(const ushort_t* __restrict__ src,
                                                  char* ldsBase, int tid) {
  const int r = tid >> 2;                          // 0..127
  const int c = ((tid & 3) ^ ((tid >> 3) & 3)) << 3;  // slot ^ ((r>>1)&3), elems
  gl2lds16(src + (size_t)r * 4096 + c, ldsBase + tid * 16);
  gl2lds16(src + (size_t)(r + 128) * 4096 + c, ldsBase + 8192 + tid * 16);
}

static __device__ __forceinline__ void gemm256_core(
    const ushort_t* __restrict__ Ahg, const ushort_t* __restrict__ Bhg,
    int m0, int n0, int kbase, int NT, char* lds, f4 (&acc)[8][4]) {
  const int tid = threadIdx.x;
  const int wid = tid >> 6;
  const int lane = tid & 63;
  const int ln = lane & 15;
  const int quad = lane >> 4;
  const int wy = wid >> 2, wx = wid & 3;
  // row's low 4 bits == ln, so (row>>1)&3 == (ln>>1)&3
  const int chunk = (quad ^ ((ln >> 1) & 3)) << 4;  // swizzled slot byte offset

  const ushort_t* Abase = Ahg + (size_t)m0 * 4096 + kbase;
  const ushort_t* Bbase = Bhg + (size_t)n0 * 4096 + kbase;

  // prologue: stage tile 0 (4 block-wide load instrs, 2 per matrix)
  stage_tile(Abase, lds, tid);
  stage_tile(Bbase, lds + 32768, tid);

  int cur = 0;
  for (int t = 0; t < NT; ++t) {
    const bool st = (t + 1 < NT);
    char* aCur = lds + cur * 16384;
    char* bCur = lds + 32768 + cur * 16384;
    if (st) {
      // issue next-tile loads; they stay in flight through this tile's MFMA
      stage_tile(Abase + (t + 1) * 32, lds + (cur ^ 1) * 16384, tid);
      stage_tile(Bbase + (t + 1) * 32, lds + 32768 + (cur ^ 1) * 16384, tid);
      WAITVM4;   // all but the 4 newest (= stage(t+1)) landed => stage(t) done
    } else {
      WAITVM0;   // last tile: drain
    }
    BAR();        // every wave confirmed ITS stage(t) portion -> tile ready
    SCHED_FENCE();  // pin ds_reads below the barrier

    half8 Af[8], Bf[4];
#pragma unroll
    for (int mi = 0; mi < 8; ++mi) {
      int row = wy * 16 + mi * 32 + ln;
      Af[mi] = *(const half8*)(aCur + row * 64 + chunk);
    }
#pragma unroll
    for (int ni = 0; ni < 4; ++ni) {
      int row = wx * 16 + ni * 64 + ln;
      Bf[ni] = *(const half8*)(bCur + row * 64 + chunk);
    }
    __builtin_amdgcn_s_setprio(1);
#pragma unroll
    for (int mi = 0; mi < 8; ++mi)
#pragma unroll
      for (int ni = 0; ni < 4; ++ni)
        acc[mi][ni] = __builtin_amdgcn_mfma_f32_16x16x32_f16(Af[mi], Bf[ni], acc[mi][ni], 0, 0, 0);
    __builtin_amdgcn_s_setprio(0);
    BAR();        // all waves done reading buf[cur] before it is re-staged
    cur ^= 1;
  }
}

// ---------------- fused QKV GEMM: (2048x4096) @ (6144x4096)^T -------------
// cols 0..4095 -> Qout fp16 (2048x4096); cols 4096..6143 -> KVout fp32
__global__ __launch_bounds__(512, 2) void gemm_qkv(const ushort_t* __restrict__ Ahg,
                                                   const ushort_t* __restrict__ Bhg,
                                                   ushort_t* __restrict__ Qout,
                                                   float* __restrict__ KVout) {
  __shared__ __align__(16) char lds[65536];
  f4 acc[8][4];
#pragma unroll
  for (int i = 0; i < 8; ++i)
#pragma unroll
    for (int j = 0; j < 4; ++j) acc[i][j] = (f4){0.f, 0.f, 0.f, 0.f};
  const int m0 = blockIdx.y * 256, n0 = blockIdx.x * 256;
  gemm256_core(Ahg, Bhg, m0, n0, 0, 128, lds, acc);

  const int tid = threadIdx.x;
  const int wid = tid >> 6, lane = tid & 63, ln = lane & 15, quad = lane >> 4;
  const int wy = wid >> 2, wx = wid & 3;
  if (n0 < 4096) {
#pragma unroll
    for (int mi = 0; mi < 8; ++mi) {
      int row = m0 + wy * 16 + mi * 32 + quad * 4;
#pragma unroll
      for (int ni = 0; ni < 4; ++ni) {
        int col = n0 + wx * 16 + ni * 64 + ln;
        ushort_t* cp = Qout + (size_t)row * 4096 + col;
#pragma unroll
        for (int r = 0; r < 4; ++r) cp[(size_t)r * 4096] = f2h(acc[mi][ni][r]);
      }
    }
  } else {
#pragma unroll
    for (int mi = 0; mi < 8; ++mi) {
      int row = m0 + wy * 16 + mi * 32 + quad * 4;
#pragma unroll
      for (int ni = 0; ni < 4; ++ni) {
        int col = n0 - 4096 + wx * 16 + ni * 64 + ln;
        float* cp = KVout + (size_t)row * 2048 + col;
#pragma unroll
        for (int r = 0; r < 4; ++r) cp[(size_t)r * 2048] = acc[mi][ni][r];
      }
    }
  }
}

// ---------------- O GEMM, split-K=2: (2048x4096) @ (4096x4096)^T ----------
__global__ __launch_bounds__(512, 2) void gemm_o(const ushort_t* __restrict__ Ahg,
                                                 const ushort_t* __restrict__ Bhg,
                                                 float* __restrict__ C0,
                                                 float* __restrict__ C1) {
  __shared__ __align__(16) char lds[65536];
  f4 acc[8][4];
#pragma unroll
  for (int i = 0; i < 8; ++i)
#pragma unroll
    for (int j = 0; j < 4; ++j) acc[i][j] = (f4){0.f, 0.f, 0.f, 0.f};
  const int m0 = blockIdx.y * 256, n0 = blockIdx.x * 256;
  const int kz = blockIdx.z * 2048;
  gemm256_core(Ahg, Bhg, m0, n0, kz, 64, lds, acc);

  const int tid = threadIdx.x;
  const int wid = tid >> 6, lane = tid & 63, ln = lane & 15, quad = lane >> 4;
  const int wy = wid >> 2, wx = wid & 3;
  float* Cp = blockIdx.z ? C1 : C0;
#pragma unroll
  for (int mi = 0; mi < 8; ++mi) {
    int row = m0 + wy * 16 + mi * 32 + quad * 4;
#pragma unroll
    for (int ni = 0; ni < 4; ++ni) {
      int col = n0 + wx * 16 + ni * 64 + ln;
      float* cp = Cp + (size_t)row * 4096 + col;
#pragma unroll
      for (int r = 0; r < 4; ++r) cp[(size_t)r * 4096] = acc[mi][ni][r];
    }
  }
}

__global__ __launch_bounds__(256) void reduce2(float* __restrict__ out,
                                               const float* __restrict__ p1, int n4) {
  int i = blockIdx.x * 256 + threadIdx.x;
  if (i >= n4) return;
  float4 a = ((const float4*)out)[i];
  float4 b = ((const float4*)p1)[i];
  a.x += b.x; a.y += b.y; a.z += b.z; a.w += b.w;
  ((float4*)out)[i] = a;
}

// ---------------- K fake-quant: per-column stats over 2048 rows -----------
__global__ __launch_bounds__(256) void kquant(float* __restrict__ KV) {
  __shared__ float s[2048];
  __shared__ float red[256];
  const int c = blockIdx.x, tid = threadIdx.x;
  float x[8];
#pragma unroll
  for (int i = 0; i < 8; i++) {
    x[i] = KV[(size_t)(tid + i * 256) * 2048 + c];
    s[tid + i * 256] = x[i];
  }
  __syncthreads();
  for (int k = 2; k <= 2048; k <<= 1)
    for (int j = k >> 1; j > 0; j >>= 1) {
      for (int i = tid; i < 2048; i += 256) {
        int l = i ^ j;
        if (l > i) {
          float a = s[i], b2 = s[l];
          bool up = ((i & k) == 0);
          if ((a > b2) == up) { s[i] = b2; s[l] = a; }
        }
      }
      __syncthreads();
    }
  float lower = s[1]    + 0.0235f * (s[2]    - s[1]);
  float upper = s[2045] + 0.9765f * (s[2046] - s[2045]);
  float med   = s[1023];
  float mx = -__builtin_inff(), mn = __builtin_inff();
#pragma unroll
  for (int i = 0; i < 8; i++) {
    bool m = (x[i] <= lower) | (x[i] >= upper);
    float t = m ? med : x[i];
    mx = fmaxf(mx, t);
    mn = fminf(mn, t);
  }
  __syncthreads();
  red[tid] = mx; __syncthreads();
  for (int off = 128; off > 0; off >>= 1) {
    if (tid < off) red[tid] = fmaxf(red[tid], red[tid + off]);
    __syncthreads();
  }
  mx = red[0]; __syncthreads();
  red[tid] = mn; __syncthreads();
  for (int off = 128; off > 0; off >>= 1) {
    if (tid < off) red[tid] = fminf(red[tid], red[tid + off]);
    __syncthreads();
  }
  mn = red[0];
  float qx = 15.0f / (mx - mn);
  float offv = mn * qx;
#pragma unroll
  for (int i = 0; i < 8; i++) {
    bool m = (x[i] <= lower) | (x[i] >= upper);
    float inp = m ? 0.f : x[i];
    float q = rintf(qx * inp - offv);
    q = fminf(fmaxf(q, 0.f), 15.f);
    float deq = (q + offv) / qx;
    float o = m ? x[i] : deq;
    if (!__builtin_isfinite(o)) o = 0.f;
    KV[(size_t)(tid + i * 256) * 2048 + c] = o;
  }
}

// ---------------- V fake-quant: per-row stats; writes fp16 rows -----------
__global__ __launch_bounds__(256) void vquant(const float* __restrict__ KV,
                                              ushort_t* __restrict__ vrow) {
  __shared__ float s[1024];
  __shared__ float red[256];
  const int rrow = blockIdx.x, tid = threadIdx.x;
  float x[4];
#pragma unroll
  for (int i = 0; i < 4; i++) {
    x[i] = KV[(size_t)rrow * 2048 + 1024 + tid + i * 256];
    s[tid + i * 256] = x[i];
  }
  __syncthreads();
  for (int k = 2; k <= 1024; k <<= 1)
    for (int j = k >> 1; j > 0; j >>= 1) {
      for (int i = tid; i < 1024; i += 256) {
        int l = i ^ j;
        if (l > i) {
          float a = s[i], b2 = s[l];
          bool up = ((i & k) == 0);
          if ((a > b2) == up) { s[i] = b2; s[l] = a; }
        }
      }
      __syncthreads();
    }
  float lower = s[0]    + 0.5115f * (s[1]    - s[0]);
  float upper = s[1022] + 0.4885f * (s[1023] - s[1022]);
  float med   = s[511];
  float mx = -__builtin_inff(), mn = __builtin_inff();
#pragma unroll
  for (int i = 0; i < 4; i++) {
    bool m = (x[i] <= lower) | (x[i] >= upper);
    float t = m ? med : x[i];
    mx = fmaxf(mx, t);
    mn = fminf(mn, t);
  }
  __syncthreads();
  red[tid] = mx; __syncthreads();
  for (int off = 128; off > 0; off >>= 1) {
    if (tid < off) red[tid] = fmaxf(red[tid], red[tid + off]);
    __syncthreads();
  }
  mx = red[0]; __syncthreads();
  red[tid] = mn; __syncthreads();
  for (int off = 128; off > 0; off >>= 1) {
    if (tid < off) red[tid] = fminf(red[tid], red[tid + off]);
    __syncthreads();
  }
  mn = red[0];
  float qx = 15.0f / (mx - mn);
  float offv = mn * qx;
#pragma unroll
  for (int i = 0; i < 4; i++) {
    bool m = (x[i] <= lower) | (x[i] >= upper);
    float inp = m ? 0.f : x[i];
    float q = rintf(qx * inp - offv);
    q = fminf(fmaxf(q, 0.f), 15.f);
    float deq = (q + offv) / qx;
    float o = m ? x[i] : deq;
    if (!__builtin_isfinite(o)) o = 0.f;
    vrow[(size_t)rrow * 1024 + tid + i * 256] = f2h(o);
  }
}

// ---------------- V transpose: vrow(2048,1024) -> vb(B,KVH,128,1024) ------
__global__ __launch_bounds__(256) void vtrans(const ushort_t* __restrict__ vrow,
                                              ushort_t* __restrict__ vb) {
  __shared__ ushort_t T[64 * 65];
  const int c0 = blockIdx.x * 64, r0 = blockIdx.y * 64;
  const int b = r0 >> 10, sbase = r0 & 1023;
#pragma unroll
  for (int i = 0; i < 2; i++) {
    int idx = threadIdx.x + i * 256;
    int r = idx >> 3, c8 = (idx & 7) * 8;
    uint4 v = *(const uint4*)(vrow + (size_t)(r0 + r) * 1024 + c0 + c8);
    const ushort_t* p = (const ushort_t*)&v;
#pragma unroll
    for (int j = 0; j < 8; j++) T[r * 65 + c8 + j] = p[j];
  }
  __syncthreads();
#pragma unroll
  for (int i = 0; i < 2; i++) {
    int idx = threadIdx.x + i * 256;
    int c = idx >> 3, s8 = (idx & 7) * 8;
    ushort_t tmp[8];
#pragma unroll
    for (int j = 0; j < 8; j++) tmp[j] = T[(s8 + j) * 65 + c];
    int gc = c0 + c;  // h*128 + d
    size_t oa = ((size_t)(b * KVHEADS + (gc >> 7)) * HDIM + (gc & 127)) * S_LEN + sbase + s8;
    *(uint4*)(vb + oa) = *(const uint4*)tmp;
  }
}

// ---------------- RoPE Q: (B,S,NH*D) fp16 -> (B,NH,S,D) fp16, prescaled ---
__global__ __launch_bounds__(256) void rope_q(const ushort_t* __restrict__ Q,
                                              const int* __restrict__ pos,
                                              ushort_t* __restrict__ qb) {
  int t = blockIdx.x * 256 + threadIdx.x;
  int i = t & 63;
  int h = (t >> 6) & 31;
  int s = (t >> 11) & 1023;
  int b = t >> 21;
  int p = pos[b * S_LEN + s];
  float inv = expf(-9.210340371976184f * ((float)i * (1.0f / 64.0f)));
  float ang = (float)p * inv;
  float sn, cs;
  sincosf(ang, &sn, &cs);
  size_t base = ((size_t)(b * S_LEN + s)) * H_DIM + h * HDIM + i;
  float x1 = h2f(Q[base]), x2 = h2f(Q[base + 64]);
  const float sc = 0.08838834764831845f;  // 1/sqrt(128)
  size_t ob = (((size_t)(b * NHEADS + h)) * S_LEN + s) * HDIM + i;
  qb[ob]      = f2h((x1 * cs - x2 * sn) * sc);
  qb[ob + 64] = f2h((x2 * cs + x1 * sn) * sc);
}

// ---------------- RoPE K from combined KV fp32 ----------------------------
__global__ __launch_bounds__(256) void rope_k(const float* __restrict__ KV,
                                              const int* __restrict__ pos,
                                              ushort_t* __restrict__ kb) {
  int t = blockIdx.x * 256 + threadIdx.x;
  int i = t & 63;
  int h = (t >> 6) & 7;
  int s = (t >> 9) & 1023;
  int b = t >> 19;
  int p = pos[b * S_LEN + s];
  float inv = expf(-9.210340371976184f * ((float)i * (1.0f / 64.0f)));
  float ang = (float)p * inv;
  float sn, cs;
  sincosf(ang, &sn, &cs);
  size_t base = ((size_t)(b * S_LEN + s)) * 2048 + h * HDIM + i;
  float k1 = KV[base], k2 = KV[base + 64];
  size_t ob = (((size_t)(b * KVHEADS + h)) * S_LEN + s) * HDIM + i;
  kb[ob]      = f2h(k1 * cs - k2 * sn);
  kb[ob + 64] = f2h(k2 * cs + k1 * sn);
}

// ---------------- Flash attention (causal, GQA), 128-query tiles ----------
__global__ __launch_bounds__(256) void attn_fwd(const ushort_t* __restrict__ qb,
                                                const ushort_t* __restrict__ kb,
                                                const ushort_t* __restrict__ vb,
                                                ushort_t* __restrict__ ob) {
  __shared__ short Ks[64 * 136];    // keys row-major [k][d], pad 8
  __shared__ short Vs[128 * 72];    // V^T [d][s], pad 8
  __shared__ short Ps[4 * 32 * 72]; // per-wave P [q][k], pad 8
  const int tid = threadIdx.x;
  const int wid = tid >> 6;
  const int lane = tid & 63;
  const int ln = lane & 15;
  const int quad = lane >> 4;
  const int q0 = blockIdx.x * 128;
  const int bh = blockIdx.y;
  const int b = bh >> 5, h = bh & 31, hk = h >> 2;

  half8 aq[2][4];
#pragma unroll
  for (int mi = 0; mi < 2; mi++) {
    const ushort_t* qrow =
        qb + (((size_t)(b * NHEADS + h)) * S_LEN + q0 + wid * 32 + mi * 16 + ln) * HDIM;
#pragma unroll
    for (int ks = 0; ks < 4; ks++) aq[mi][ks] = *(const half8*)(qrow + ks * 32 + quad * 8);
  }

  f4 accO[2][8];
#pragma unroll
  for (int mi = 0; mi < 2; mi++)
#pragma unroll
    for (int i = 0; i < 8; i++) accO[mi][i] = (f4){0.f, 0.f, 0.f, 0.f};
  float mr[2][4], lr[2][4];
#pragma unroll
  for (int mi = 0; mi < 2; mi++)
#pragma unroll
    for (int r = 0; r < 4; r++) { mr[mi][r] = -__builtin_inff(); lr[mi][r] = 0.f; }

  const ushort_t* kbp = kb + ((size_t)(b * KVHEADS + hk)) * S_LEN * HDIM;
  const ushort_t* vbp = vb + ((size_t)(b * KVHEADS + hk)) * HDIM * S_LEN;

  const int ktiles = 2 * blockIdx.x + 2;
  for (int kt = 0; kt < ktiles; kt++) {
    const int k0 = kt * 64;
    __syncthreads();
#pragma unroll
    for (int cc = 0; cc < 4; cc++) {
      int idx = tid + cc * 256;
      int r = idx >> 4, c8 = idx & 15;
      *(uint4*)&Ks[r * 136 + c8 * 8] = *(const uint4*)(kbp + (size_t)(k0 + r) * HDIM + c8 * 8);
      int d = idx >> 3, s8 = idx & 7;
      *(uint4*)&Vs[d * 72 + s8 * 8] = *(const uint4*)(vbp + (size_t)d * S_LEN + k0 + s8 * 8);
    }
    __syncthreads();

    if (q0 + wid * 32 + 31 < k0) continue;  // fully masked wave (uniform branch)

    f4 sc[2][4];
#pragma unroll
    for (int mi = 0; mi < 2; mi++)
#pragma unroll
      for (int nt = 0; nt < 4; nt++) sc[mi][nt] = (f4){0.f, 0.f, 0.f, 0.f};
#pragma unroll
    for (int nt = 0; nt < 4; nt++) {
      half8 bk[4];
#pragma unroll
      for (int ks = 0; ks < 4; ks++)
        bk[ks] = *(const half8*)&Ks[(nt * 16 + ln) * 136 + ks * 32 + quad * 8];
#pragma unroll
      for (int mi = 0; mi < 2; mi++)
#pragma unroll
        for (int ks = 0; ks < 4; ks++)
          sc[mi][nt] = __builtin_amdgcn_mfma_f32_16x16x32_f16(aq[mi][ks], bk[ks], sc[mi][nt], 0, 0, 0);
    }
#pragma unroll
    for (int mi = 0; mi < 2; mi++)
#pragma unroll
      for (int r = 0; r < 4; r++) {
        int mq = q0 + wid * 32 + mi * 16 + quad * 4 + r;
#pragma unroll
        for (int nt = 0; nt < 4; nt++) {
          int nk = k0 + nt * 16 + ln;
          if (nk > mq) sc[mi][nt][r] = -1e30f;
        }
      }
    float al[2][4];
#pragma unroll
    for (int mi = 0; mi < 2; mi++)
#pragma unroll
      for (int r = 0; r < 4; r++) {
        float tm = fmaxf(fmaxf(sc[mi][0][r], sc[mi][1][r]), fmaxf(sc[mi][2][r], sc[mi][3][r]));
        tm = fmaxf(tm, __shfl_xor(tm, 1));
        tm = fmaxf(tm, __shfl_xor(tm, 2));
        tm = fmaxf(tm, __shfl_xor(tm, 4));
        tm = fmaxf(tm, __shfl_xor(tm, 8));
        float mnew = fmaxf(mr[mi][r], tm);
        al[mi][r] = __expf(mr[mi][r] - mnew);
        mr[mi][r] = mnew;
        float ls = 0.f;
#pragma unroll
        for (int nt = 0; nt < 4; nt++) {
          float pp = __expf(sc[mi][nt][r] - mnew);
          sc[mi][nt][r] = pp;
          ls += pp;
        }
        ls += __shfl_xor(ls, 1);
        ls += __shfl_xor(ls, 2);
        ls += __shfl_xor(ls, 4);
        ls += __shfl_xor(ls, 8);
        lr[mi][r] = lr[mi][r] * al[mi][r] + ls;
      }
#pragma unroll
    for (int mi = 0; mi < 2; mi++)
#pragma unroll
      for (int dt = 0; dt < 8; dt++)
#pragma unroll
        for (int r = 0; r < 4; r++) accO[mi][dt][r] *= al[mi][r];
#pragma unroll
    for (int mi = 0; mi < 2; mi++)
#pragma unroll
      for (int r = 0; r < 4; r++)
#pragma unroll
        for (int nt = 0; nt < 4; nt++)
          Ps[wid * 2304 + (mi * 16 + quad * 4 + r) * 72 + nt * 16 + ln] =
              (short)f2h(sc[mi][nt][r]);
    half8 ap[2][2];
#pragma unroll
    for (int mi = 0; mi < 2; mi++)
#pragma unroll
      for (int k2 = 0; k2 < 2; k2++)
        ap[mi][k2] = *(const half8*)&Ps[wid * 2304 + (mi * 16 + ln) * 72 + k2 * 32 + quad * 8];
#pragma unroll
    for (int dt = 0; dt < 8; dt++)
#pragma unroll
      for (int k2 = 0; k2 < 2; k2++) {
        half8 bv = *(const half8*)&Vs[(dt * 16 + ln) * 72 + k2 * 32 + quad * 8];
#pragma unroll
        for (int mi = 0; mi < 2; mi++)
          accO[mi][dt] = __builtin_amdgcn_mfma_f32_16x16x32_f16(ap[mi][k2], bv, accO[mi][dt], 0, 0, 0);
      }
  }
#pragma unroll
  for (int mi = 0; mi < 2; mi++)
#pragma unroll
    for (int r = 0; r < 4; r++) {
      float invl = 1.0f / lr[mi][r];
      int so = q0 + wid * 32 + mi * 16 + quad * 4 + r;
      size_t obase = ((size_t)(b * S_LEN + so)) * H_DIM + h * HDIM;
#pragma unroll
      for (int dt = 0; dt < 8; dt++)
        ob[obase + dt * 16 + ln] = f2h(accO[mi][dt][r] * invl);
    }
}

extern "C" void kernel_launch(void* const* d_in, const int* in_sizes, int n_in,
                              void* d_out, int out_size, void* d_ws, size_t ws_size,
                              hipStream_t stream) {
  const float* hidden = (const float*)d_in[0];
  const float* Wq = (const float*)d_in[1];
  const float* Wk = (const float*)d_in[2];
  const float* Wv = (const float*)d_in[3];
  const float* Wo = (const float*)d_in[4];
  const int* pos = (const int*)d_in[5];
  float* outp = (float*)d_out;

  // workspace layout (~113 MB) with lifetime-based reuse
  char* ws = (char*)d_ws;
  ushort_t* Wall = (ushort_t*)ws; ws += (size_t)6144 * 4096 * 2;  // [Wq;Wk;Wv] fp16; later Wo fp16 + qb
  ushort_t* hh   = (ushort_t*)ws; ws += (size_t)2048 * 4096 * 2;  // hidden fp16; later ab
  ushort_t* Qf16 = (ushort_t*)ws; ws += (size_t)2048 * 4096 * 2;  // Q proj out; later P1 (w/ KVf)
  float*    KVf  = (float*)ws;    ws += (size_t)2048 * 2048 * 4;  // KV proj out fp32
  ushort_t* vrow = (ushort_t*)ws; ws += (size_t)2048 * 1024 * 2;  // quantized V rows fp16
  ushort_t* kb   = (ushort_t*)ws; ws += (size_t)2048 * 1024 * 2;  // (B,KVH,S,D) fp16
  ushort_t* vb   = (ushort_t*)ws;                                 // (B,KVH,D,S) fp16

  ushort_t* Woh = Wall;                               // Wo fp16 (after QKV GEMM)
  ushort_t* qb  = Wall + (size_t)4096 * 4096;         // (B,NH,S,D), overlays Wk/Wv fp16
  ushort_t* ab  = hh;                                 // attn out (B,S,NH*D)
  float*    P1  = (float*)Qf16;                       // split-K partial, overlays Qf16+KVf

  // conversions to fp16
  cvt16<<<8192, 256, 0, stream>>>(hidden, hh, 2048 * 4096 / 4);
  cvt16<<<16384, 256, 0, stream>>>(Wq, Wall, 4096 * 4096 / 4);
  cvt16<<<4096, 256, 0, stream>>>(Wk, Wall + (size_t)4096 * 4096, 1024 * 4096 / 4);
  cvt16<<<4096, 256, 0, stream>>>(Wv, Wall + (size_t)5120 * 4096, 1024 * 4096 / 4);

  // fused QKV projection (256^2 tiles, 24x8 grid, 512 threads, 64 KiB LDS)
  gemm_qkv<<<dim3(24, 8), 512, 0, stream>>>(hh, Wall, Qf16, KVf);

  // fake-quant (exact order statistics)
  kquant<<<1024, 256, 0, stream>>>(KVf);
  vquant<<<2048, 256, 0, stream>>>(KVf, vrow);
  vtrans<<<dim3(16, 32), 256, 0, stream>>>(vrow, vb);

  // RoPE + layout (qb overlays dead Wk/Wv region)
  rope_q<<<16384, 256, 0, stream>>>(Qf16, pos, qb);
  rope_k<<<4096, 256, 0, stream>>>(KVf, pos, kb);

  // Wo conversion into Wall head (Wq fp16 dead)
  cvt16<<<16384, 256, 0, stream>>>(Wo, Woh, 4096 * 4096 / 4);

  // attention
  attn_fwd<<<dim3(8, 64), 256, 0, stream>>>(qb, kb, vb, ab);

  // output projection, split-K=2 (z=0 -> outp, z=1 -> P1), then reduce
  gemm_o<<<dim3(16, 8, 2), 512, 0, stream>>>(ab, Woh, outp, P1);
  reduce2<<<8192, 256, 0, stream>>>(outp, P1, 2048 * 4096 / 4);
}

// Round 5
// 659.003 us; speedup vs baseline: 1.1677x; 1.0245x over previous
//
#include <hip/hip_runtime.h>

#define S_LEN 1024
#define B_SZ 2
#define H_DIM 4096
#define NHEADS 32
#define KVHEADS 8
#define HDIM 128

typedef _Float16 half8 __attribute__((ext_vector_type(8)));
typedef float f4 __attribute__((ext_vector_type(4)));
typedef unsigned short ushort_t;

static __device__ __forceinline__ ushort_t f2h(float x) {
  _Float16 h = (_Float16)x;
  return __builtin_bit_cast(unsigned short, h);
}
static __device__ __forceinline__ float h2f(ushort_t u) {
  return (float)__builtin_bit_cast(_Float16, u);
}

// async global->LDS, 16B per lane. LDS dest must be wave-uniform base + lane*16.
static __device__ __forceinline__ void gl2lds16(const void* g, void* l) {
  __builtin_amdgcn_global_load_lds(
      (const __attribute__((address_space(1))) unsigned int*)(unsigned long long)(uintptr_t)g,
      (__attribute__((address_space(3))) unsigned int*)(unsigned int)(uintptr_t)l,
      16, 0, 0);
}

#define WAITVM4 asm volatile("s_waitcnt vmcnt(4)" ::: "memory")
#define WAITVM0 asm volatile("s_waitcnt vmcnt(0)" ::: "memory")
#define BAR() __builtin_amdgcn_s_barrier()
#define SCHED_FENCE() __builtin_amdgcn_sched_barrier(0)

// ---------------- fp32 -> fp16 conversion --------------------------------
__global__ __launch_bounds__(256) void cvt16(const float* __restrict__ x,
                                             ushort_t* __restrict__ h, int n4) {
  int i = blockIdx.x * 256 + threadIdx.x;
  if (i >= n4) return;
  float4 v = ((const float4*)x)[i];
  uint2 hp;
  hp.x = (unsigned)f2h(v.x) | ((unsigned)f2h(v.y) << 16);
  hp.y = (unsigned)f2h(v.z) | ((unsigned)f2h(v.w) << 16);
  ((uint2*)h)[i] = hp;
}

// ---------------- 256x256 pipelined GEMM core (64 KiB static LDS) ---------
// (unchanged from round 4 — see r3/r4 notes: counted vmcnt pipeline +
// parity-independent slot swizzle (r>>1)&3, 2-way = free)

static __device__ __forceinline__ void stage_tile(const ushort_t* __restrict__ src,
                                                  char* ldsBase, int tid) {
  const int r = tid >> 2;                          // 0..127
  const int c = ((tid & 3) ^ ((tid >> 3) & 3)) << 3;  // slot ^ ((r>>1)&3), elems
  gl2lds16(src + (size_t)r * 4096 + c, ldsBase + tid * 16);
  gl2lds16(src + (size_t)(r + 128) * 4096 + c, ldsBase + 8192 + tid * 16);
}

static __device__ __forceinline__ void gemm256_core(
    const ushort_t* __restrict__ Ahg, const ushort_t* __restrict__ Bhg,
    int m0, int n0, int kbase, int NT, char* lds, f4 (&acc)[8][4]) {
  const int tid = threadIdx.x;
  const int wid = tid >> 6;
  const int lane = tid & 63;
  const int ln = lane & 15;
  const int quad = lane >> 4;
  const int wy = wid >> 2, wx = wid & 3;
  // row's low 4 bits == ln, so (row>>1)&3 == (ln>>1)&3
  const int chunk = (quad ^ ((ln >> 1) & 3)) << 4;  // swizzled slot byte offset

  const ushort_t* Abase = Ahg + (size_t)m0 * 4096 + kbase;
  const ushort_t* Bbase = Bhg + (size_t)n0 * 4096 + kbase;

  // prologue: stage tile 0 (4 block-wide load instrs, 2 per matrix)
  stage_tile(Abase, lds, tid);
  stage_tile(Bbase, lds + 32768, tid);

  int cur = 0;
  for (int t = 0; t < NT; ++t) {
    const bool st = (t + 1 < NT);
    char* aCur = lds + cur * 16384;
    char* bCur = lds + 32768 + cur * 16384;
    if (st) {
      // issue next-tile loads; they stay in flight through this tile's MFMA
      stage_tile(Abase + (t + 1) * 32, lds + (cur ^ 1) * 16384, tid);
      stage_tile(Bbase + (t + 1) * 32, lds + 32768 + (cur ^ 1) * 16384, tid);
      WAITVM4;   // all but the 4 newest (= stage(t+1)) landed => stage(t) done
    } else {
      WAITVM0;   // last tile: drain
    }
    BAR();        // every wave confirmed ITS stage(t) portion -> tile ready
    SCHED_FENCE();  // pin ds_reads below the barrier

    half8 Af[8], Bf[4];
#pragma unroll
    for (int mi = 0; mi < 8; ++mi) {
      int row = wy * 16 + mi * 32 + ln;
      Af[mi] = *(const half8*)(aCur + row * 64 + chunk);
    }
#pragma unroll
    for (int ni = 0; ni < 4; ++ni) {
      int row = wx * 16 + ni * 64 + ln;
      Bf[ni] = *(const half8*)(bCur + row * 64 + chunk);
    }
    __builtin_amdgcn_s_setprio(1);
#pragma unroll
    for (int mi = 0; mi < 8; ++mi)
#pragma unroll
      for (int ni = 0; ni < 4; ++ni)
        acc[mi][ni] = __builtin_amdgcn_mfma_f32_16x16x32_f16(Af[mi], Bf[ni], acc[mi][ni], 0, 0, 0);
    __builtin_amdgcn_s_setprio(0);
    BAR();        // all waves done reading buf[cur] before it is re-staged
    cur ^= 1;
  }
}

// ---------------- fused QKV GEMM: (2048x4096) @ (6144x4096)^T -------------
// cols 0..4095 -> Qout fp16 (2048x4096); cols 4096..6143 -> KVout fp32
__global__ __launch_bounds__(512, 2) void gemm_qkv(const ushort_t* __restrict__ Ahg,
                                                   const ushort_t* __restrict__ Bhg,
                                                   ushort_t* __restrict__ Qout,
                                                   float* __restrict__ KVout) {
  __shared__ __align__(16) char lds[65536];
  f4 acc[8][4];
#pragma unroll
  for (int i = 0; i < 8; ++i)
#pragma unroll
    for (int j = 0; j < 4; ++j) acc[i][j] = (f4){0.f, 0.f, 0.f, 0.f};
  const int m0 = blockIdx.y * 256, n0 = blockIdx.x * 256;
  gemm256_core(Ahg, Bhg, m0, n0, 0, 128, lds, acc);

  const int tid = threadIdx.x;
  const int wid = tid >> 6, lane = tid & 63, ln = lane & 15, quad = lane >> 4;
  const int wy = wid >> 2, wx = wid & 3;
  if (n0 < 4096) {
#pragma unroll
    for (int mi = 0; mi < 8; ++mi) {
      int row = m0 + wy * 16 + mi * 32 + quad * 4;
#pragma unroll
      for (int ni = 0; ni < 4; ++ni) {
        int col = n0 + wx * 16 + ni * 64 + ln;
        ushort_t* cp = Qout + (size_t)row * 4096 + col;
#pragma unroll
        for (int r = 0; r < 4; ++r) cp[(size_t)r * 4096] = f2h(acc[mi][ni][r]);
      }
    }
  } else {
#pragma unroll
    for (int mi = 0; mi < 8; ++mi) {
      int row = m0 + wy * 16 + mi * 32 + quad * 4;
#pragma unroll
      for (int ni = 0; ni < 4; ++ni) {
        int col = n0 - 4096 + wx * 16 + ni * 64 + ln;
        float* cp = KVout + (size_t)row * 2048 + col;
#pragma unroll
        for (int r = 0; r < 4; ++r) cp[(size_t)r * 2048] = acc[mi][ni][r];
      }
    }
  }
}

// ---------------- O GEMM, split-K=2: (2048x4096) @ (4096x4096)^T ----------
__global__ __launch_bounds__(512, 2) void gemm_o(const ushort_t* __restrict__ Ahg,
                                                 const ushort_t* __restrict__ Bhg,
                                                 float* __restrict__ C0,
                                                 float* __restrict__ C1) {
  __shared__ __align__(16) char lds[65536];
  f4 acc[8][4];
#pragma unroll
  for (int i = 0; i < 8; ++i)
#pragma unroll
    for (int j = 0; j < 4; ++j) acc[i][j] = (f4){0.f, 0.f, 0.f, 0.f};
  const int m0 = blockIdx.y * 256, n0 = blockIdx.x * 256;
  const int kz = blockIdx.z * 2048;
  gemm256_core(Ahg, Bhg, m0, n0, kz, 64, lds, acc);

  const int tid = threadIdx.x;
  const int wid = tid >> 6, lane = tid & 63, ln = lane & 15, quad = lane >> 4;
  const int wy = wid >> 2, wx = wid & 3;
  float* Cp = blockIdx.z ? C1 : C0;
#pragma unroll
  for (int mi = 0; mi < 8; ++mi) {
    int row = m0 + wy * 16 + mi * 32 + quad * 4;
#pragma unroll
    for (int ni = 0; ni < 4; ++ni) {
      int col = n0 + wx * 16 + ni * 64 + ln;
      float* cp = Cp + (size_t)row * 4096 + col;
#pragma unroll
      for (int r = 0; r < 4; ++r) cp[(size_t)r * 4096] = acc[mi][ni][r];
    }
  }
}

__global__ __launch_bounds__(256) void reduce2(float* __restrict__ out,
                                               const float* __restrict__ p1, int n4) {
  int i = blockIdx.x * 256 + threadIdx.x;
  if (i >= n4) return;
  float4 a = ((const float4*)out)[i];
  float4 b = ((const float4*)p1)[i];
  a.x += b.x; a.y += b.y; a.z += b.z; a.w += b.w;
  ((float4*)out)[i] = a;
}

// ---------------- K fake-quant: per-column stats over 2048 rows -----------
__global__ __launch_bounds__(256) void kquant(float* __restrict__ KV) {
  __shared__ float s[2048];
  __shared__ float red[256];
  const int c = blockIdx.x, tid = threadIdx.x;
  float x[8];
#pragma unroll
  for (int i = 0; i < 8; i++) {
    x[i] = KV[(size_t)(tid + i * 256) * 2048 + c];
    s[tid + i * 256] = x[i];
  }
  __syncthreads();
  for (int k = 2; k <= 2048; k <<= 1)
    for (int j = k >> 1; j > 0; j >>= 1) {
      for (int i = tid; i < 2048; i += 256) {
        int l = i ^ j;
        if (l > i) {
          float a = s[i], b2 = s[l];
          bool up = ((i & k) == 0);
          if ((a > b2) == up) { s[i] = b2; s[l] = a; }
        }
      }
      __syncthreads();
    }
  float lower = s[1]    + 0.0235f * (s[2]    - s[1]);
  float upper = s[2045] + 0.9765f * (s[2046] - s[2045]);
  float med   = s[1023];
  float mx = -__builtin_inff(), mn = __builtin_inff();
#pragma unroll
  for (int i = 0; i < 8; i++) {
    bool m = (x[i] <= lower) | (x[i] >= upper);
    float t = m ? med : x[i];
    mx = fmaxf(mx, t);
    mn = fminf(mn, t);
  }
  __syncthreads();
  red[tid] = mx; __syncthreads();
  for (int off = 128; off > 0; off >>= 1) {
    if (tid < off) red[tid] = fmaxf(red[tid], red[tid + off]);
    __syncthreads();
  }
  mx = red[0]; __syncthreads();
  red[tid] = mn; __syncthreads();
  for (int off = 128; off > 0; off >>= 1) {
    if (tid < off) red[tid] = fminf(red[tid], red[tid + off]);
    __syncthreads();
  }
  mn = red[0];
  float qx = 15.0f / (mx - mn);
  float offv = mn * qx;
#pragma unroll
  for (int i = 0; i < 8; i++) {
    bool m = (x[i] <= lower) | (x[i] >= upper);
    float inp = m ? 0.f : x[i];
    float q = rintf(qx * inp - offv);
    q = fminf(fmaxf(q, 0.f), 15.f);
    float deq = (q + offv) / qx;
    float o = m ? x[i] : deq;
    if (!__builtin_isfinite(o)) o = 0.f;
    KV[(size_t)(tid + i * 256) * 2048 + c] = o;
  }
}

// ---------------- V fake-quant: per-row stats; writes fp16 rows -----------
__global__ __launch_bounds__(256) void vquant(const float* __restrict__ KV,
                                              ushort_t* __restrict__ vrow) {
  __shared__ float s[1024];
  __shared__ float red[256];
  const int rrow = blockIdx.x, tid = threadIdx.x;
  float x[4];
#pragma unroll
  for (int i = 0; i < 4; i++) {
    x[i] = KV[(size_t)rrow * 2048 + 1024 + tid + i * 256];
    s[tid + i * 256] = x[i];
  }
  __syncthreads();
  for (int k = 2; k <= 1024; k <<= 1)
    for (int j = k >> 1; j > 0; j >>= 1) {
      for (int i = tid; i < 1024; i += 256) {
        int l = i ^ j;
        if (l > i) {
          float a = s[i], b2 = s[l];
          bool up = ((i & k) == 0);
          if ((a > b2) == up) { s[i] = b2; s[l] = a; }
        }
      }
      __syncthreads();
    }
  float lower = s[0]    + 0.5115f * (s[1]    - s[0]);
  float upper = s[1022] + 0.4885f * (s[1023] - s[1022]);
  float med   = s[511];
  float mx = -__builtin_inff(), mn = __builtin_inff();
#pragma unroll
  for (int i = 0; i < 4; i++) {
    bool m = (x[i] <= lower) | (x[i] >= upper);
    float t = m ? med : x[i];
    mx = fmaxf(mx, t);
    mn = fminf(mn, t);
  }
  __syncthreads();
  red[tid] = mx; __syncthreads();
  for (int off = 128; off > 0; off >>= 1) {
    if (tid < off) red[tid] = fmaxf(red[tid], red[tid + off]);
    __syncthreads();
  }
  mx = red[0]; __syncthreads();
  red[tid] = mn; __syncthreads();
  for (int off = 128; off > 0; off >>= 1) {
    if (tid < off) red[tid] = fminf(red[tid], red[tid + off]);
    __syncthreads();
  }
  mn = red[0];
  float qx = 15.0f / (mx - mn);
  float offv = mn * qx;
#pragma unroll
  for (int i = 0; i < 4; i++) {
    bool m = (x[i] <= lower) | (x[i] >= upper);
    float inp = m ? 0.f : x[i];
    float q = rintf(qx * inp - offv);
    q = fminf(fmaxf(q, 0.f), 15.f);
    float deq = (q + offv) / qx;
    float o = m ? x[i] : deq;
    if (!__builtin_isfinite(o)) o = 0.f;
    vrow[(size_t)rrow * 1024 + tid + i * 256] = f2h(o);
  }
}

// ---------------- V transpose: vrow(2048,1024) -> vb(B,KVH,128,1024) ------
__global__ __launch_bounds__(256) void vtrans(const ushort_t* __restrict__ vrow,
                                              ushort_t* __restrict__ vb) {
  __shared__ ushort_t T[64 * 65];
  const int c0 = blockIdx.x * 64, r0 = blockIdx.y * 64;
  const int b = r0 >> 10, sbase = r0 & 1023;
#pragma unroll
  for (int i = 0; i < 2; i++) {
    int idx = threadIdx.x + i * 256;
    int r = idx >> 3, c8 = (idx & 7) * 8;
    uint4 v = *(const uint4*)(vrow + (size_t)(r0 + r) * 1024 + c0 + c8);
    const ushort_t* p = (const ushort_t*)&v;
#pragma unroll
    for (int j = 0; j < 8; j++) T[r * 65 + c8 + j] = p[j];
  }
  __syncthreads();
#pragma unroll
  for (int i = 0; i < 2; i++) {
    int idx = threadIdx.x + i * 256;
    int c = idx >> 3, s8 = (idx & 7) * 8;
    ushort_t tmp[8];
#pragma unroll
    for (int j = 0; j < 8; j++) tmp[j] = T[(s8 + j) * 65 + c];
    int gc = c0 + c;  // h*128 + d
    size_t oa = ((size_t)(b * KVHEADS + (gc >> 7)) * HDIM + (gc & 127)) * S_LEN + sbase + s8;
    *(uint4*)(vb + oa) = *(const uint4*)tmp;
  }
}

// ---------------- RoPE Q: (B,S,NH*D) fp16 -> (B,NH,S,D) fp16, prescaled ---
__global__ __launch_bounds__(256) void rope_q(const ushort_t* __restrict__ Q,
                                              const int* __restrict__ pos,
                                              ushort_t* __restrict__ qb) {
  int t = blockIdx.x * 256 + threadIdx.x;
  int i = t & 63;
  int h = (t >> 6) & 31;
  int s = (t >> 11) & 1023;
  int b = t >> 21;
  int p = pos[b * S_LEN + s];
  float inv = expf(-9.210340371976184f * ((float)i * (1.0f / 64.0f)));
  float ang = (float)p * inv;
  float sn, cs;
  sincosf(ang, &sn, &cs);
  size_t base = ((size_t)(b * S_LEN + s)) * H_DIM + h * HDIM + i;
  float x1 = h2f(Q[base]), x2 = h2f(Q[base + 64]);
  const float sc = 0.08838834764831845f;  // 1/sqrt(128)
  size_t ob = (((size_t)(b * NHEADS + h)) * S_LEN + s) * HDIM + i;
  qb[ob]      = f2h((x1 * cs - x2 * sn) * sc);
  qb[ob + 64] = f2h((x2 * cs + x1 * sn) * sc);
}

// ---------------- RoPE K from combined KV fp32 ----------------------------
__global__ __launch_bounds__(256) void rope_k(const float* __restrict__ KV,
                                              const int* __restrict__ pos,
                                              ushort_t* __restrict__ kb) {
  int t = blockIdx.x * 256 + threadIdx.x;
  int i = t & 63;
  int h = (t >> 6) & 7;
  int s = (t >> 9) & 1023;
  int b = t >> 19;
  int p = pos[b * S_LEN + s];
  float inv = expf(-9.210340371976184f * ((float)i * (1.0f / 64.0f)));
  float ang = (float)p * inv;
  float sn, cs;
  sincosf(ang, &sn, &cs);
  size_t base = ((size_t)(b * S_LEN + s)) * 2048 + h * HDIM + i;
  float k1 = KV[base], k2 = KV[base + 64];
  size_t ob = (((size_t)(b * KVHEADS + h)) * S_LEN + s) * HDIM + i;
  kb[ob]      = f2h(k1 * cs - k2 * sn);
  kb[ob + 64] = f2h(k2 * cs + k1 * sn);
}

// ---------------- Flash attention (causal, GQA) ---------------------------
// Work-balanced: grid (4,64); block bx processes TWO 128-row q-tiles
// sequentially: tile bx (2bx+2 K-iters) and tile 7-bx (16-2bx K-iters) =
// exactly 18 iters per block. 256 blocks = 1/CU, deterministic balance.
// (r4 post-mortem: old (8,64) grid put same-bx blocks on one CU -> 4..32
// iter spread; dispatch time was set by the 32-iter CUs.)
__global__ __launch_bounds__(256) void attn_fwd(const ushort_t* __restrict__ qb,
                                                const ushort_t* __restrict__ kb,
                                                const ushort_t* __restrict__ vb,
                                                ushort_t* __restrict__ ob) {
  __shared__ short Ks[64 * 136];    // keys row-major [k][d], pad 8
  __shared__ short Vs[128 * 72];    // V^T [d][s], pad 8
  __shared__ short Ps[4 * 32 * 72]; // per-wave P [q][k], pad 8
  const int tid = threadIdx.x;
  const int wid = tid >> 6;
  const int lane = tid & 63;
  const int ln = lane & 15;
  const int quad = lane >> 4;
  const int bx = blockIdx.x;
  const int bh = blockIdx.y;
  const int b = bh >> 5, h = bh & 31, hk = h >> 2;

  const ushort_t* kbp = kb + ((size_t)(b * KVHEADS + hk)) * S_LEN * HDIM;
  const ushort_t* vbp = vb + ((size_t)(b * KVHEADS + hk)) * HDIM * S_LEN;

  for (int half = 0; half < 2; ++half) {
    const int qt = half ? (7 - bx) : bx;
    const int q0 = qt * 128;
    const int ktiles = 2 * qt + 2;

    half8 aq[2][4];
#pragma unroll
    for (int mi = 0; mi < 2; mi++) {
      const ushort_t* qrow =
          qb + (((size_t)(b * NHEADS + h)) * S_LEN + q0 + wid * 32 + mi * 16 + ln) * HDIM;
#pragma unroll
      for (int ks = 0; ks < 4; ks++) aq[mi][ks] = *(const half8*)(qrow + ks * 32 + quad * 8);
    }

    f4 accO[2][8];
#pragma unroll
    for (int mi = 0; mi < 2; mi++)
#pragma unroll
      for (int i = 0; i < 8; i++) accO[mi][i] = (f4){0.f, 0.f, 0.f, 0.f};
    float mr[2][4], lr[2][4];
#pragma unroll
    for (int mi = 0; mi < 2; mi++)
#pragma unroll
      for (int r = 0; r < 4; r++) { mr[mi][r] = -__builtin_inff(); lr[mi][r] = 0.f; }

    for (int kt = 0; kt < ktiles; kt++) {
      const int k0 = kt * 64;
      __syncthreads();
#pragma unroll
      for (int cc = 0; cc < 4; cc++) {
        int idx = tid + cc * 256;
        int r = idx >> 4, c8 = idx & 15;
        *(uint4*)&Ks[r * 136 + c8 * 8] = *(const uint4*)(kbp + (size_t)(k0 + r) * HDIM + c8 * 8);
        int d = idx >> 3, s8 = idx & 7;
        *(uint4*)&Vs[d * 72 + s8 * 8] = *(const uint4*)(vbp + (size_t)d * S_LEN + k0 + s8 * 8);
      }
      __syncthreads();

      if (q0 + wid * 32 + 31 < k0) continue;  // fully masked wave (uniform branch)

      f4 sc[2][4];
#pragma unroll
      for (int mi = 0; mi < 2; mi++)
#pragma unroll
        for (int nt = 0; nt < 4; nt++) sc[mi][nt] = (f4){0.f, 0.f, 0.f, 0.f};
#pragma unroll
      for (int nt = 0; nt < 4; nt++) {
        half8 bk[4];
#pragma unroll
        for (int ks = 0; ks < 4; ks++)
          bk[ks] = *(const half8*)&Ks[(nt * 16 + ln) * 136 + ks * 32 + quad * 8];
#pragma unroll
        for (int mi = 0; mi < 2; mi++)
#pragma unroll
          for (int ks = 0; ks < 4; ks++)
            sc[mi][nt] = __builtin_amdgcn_mfma_f32_16x16x32_f16(aq[mi][ks], bk[ks], sc[mi][nt], 0, 0, 0);
      }
#pragma unroll
      for (int mi = 0; mi < 2; mi++)
#pragma unroll
        for (int r = 0; r < 4; r++) {
          int mq = q0 + wid * 32 + mi * 16 + quad * 4 + r;
#pragma unroll
          for (int nt = 0; nt < 4; nt++) {
            int nk = k0 + nt * 16 + ln;
            if (nk > mq) sc[mi][nt][r] = -1e30f;
          }
        }
      float al[2][4];
#pragma unroll
      for (int mi = 0; mi < 2; mi++)
#pragma unroll
        for (int r = 0; r < 4; r++) {
          float tm = fmaxf(fmaxf(sc[mi][0][r], sc[mi][1][r]), fmaxf(sc[mi][2][r], sc[mi][3][r]));
          tm = fmaxf(tm, __shfl_xor(tm, 1));
          tm = fmaxf(tm, __shfl_xor(tm, 2));
          tm = fmaxf(tm, __shfl_xor(tm, 4));
          tm = fmaxf(tm, __shfl_xor(tm, 8));
          float mnew = fmaxf(mr[mi][r], tm);
          al[mi][r] = __expf(mr[mi][r] - mnew);
          mr[mi][r] = mnew;
          float ls = 0.f;
#pragma unroll
          for (int nt = 0; nt < 4; nt++) {
            float pp = __expf(sc[mi][nt][r] - mnew);
            sc[mi][nt][r] = pp;
            ls += pp;
          }
          ls += __shfl_xor(ls, 1);
          ls += __shfl_xor(ls, 2);
          ls += __shfl_xor(ls, 4);
          ls += __shfl_xor(ls, 8);
          lr[mi][r] = lr[mi][r] * al[mi][r] + ls;
        }
#pragma unroll
      for (int mi = 0; mi < 2; mi++)
#pragma unroll
        for (int dt = 0; dt < 8; dt++)
#pragma unroll
          for (int r = 0; r < 4; r++) accO[mi][dt][r] *= al[mi][r];
#pragma unroll
      for (int mi = 0; mi < 2; mi++)
#pragma unroll
        for (int r = 0; r < 4; r++)
#pragma unroll
          for (int nt = 0; nt < 4; nt++)
            Ps[wid * 2304 + (mi * 16 + quad * 4 + r) * 72 + nt * 16 + ln] =
                (short)f2h(sc[mi][nt][r]);
      half8 ap[2][2];
#pragma unroll
      for (int mi = 0; mi < 2; mi++)
#pragma unroll
        for (int k2 = 0; k2 < 2; k2++)
          ap[mi][k2] = *(const half8*)&Ps[wid * 2304 + (mi * 16 + ln) * 72 + k2 * 32 + quad * 8];
#pragma unroll
      for (int dt = 0; dt < 8; dt++)
#pragma unroll
        for (int k2 = 0; k2 < 2; k2++) {
          half8 bv = *(const half8*)&Vs[(dt * 16 + ln) * 72 + k2 * 32 + quad * 8];
#pragma unroll
          for (int mi = 0; mi < 2; mi++)
            accO[mi][dt] = __builtin_amdgcn_mfma_f32_16x16x32_f16(ap[mi][k2], bv, accO[mi][dt], 0, 0, 0);
        }
    }
#pragma unroll
    for (int mi = 0; mi < 2; mi++)
#pragma unroll
      for (int r = 0; r < 4; r++) {
        float invl = 1.0f / lr[mi][r];
        int so = q0 + wid * 32 + mi * 16 + quad * 4 + r;
        size_t obase = ((size_t)(b * S_LEN + so)) * H_DIM + h * HDIM;
#pragma unroll
        for (int dt = 0; dt < 8; dt++)
          ob[obase + dt * 16 + ln] = f2h(accO[mi][dt][r] * invl);
      }
  }
}

extern "C" void kernel_launch(void* const* d_in, const int* in_sizes, int n_in,
                              void* d_out, int out_size, void* d_ws, size_t ws_size,
                              hipStream_t stream) {
  const float* hidden = (const float*)d_in[0];
  const float* Wq = (const float*)d_in[1];
  const float* Wk = (const float*)d_in[2];
  const float* Wv = (const float*)d_in[3];
  const float* Wo = (const float*)d_in[4];
  const int* pos = (const int*)d_in[5];
  float* outp = (float*)d_out;

  // workspace layout (~113 MB) with lifetime-based reuse
  char* ws = (char*)d_ws;
  ushort_t* Wall = (ushort_t*)ws; ws += (size_t)6144 * 4096 * 2;  // [Wq;Wk;Wv] fp16; later Wo fp16 + qb
  ushort_t* hh   = (ushort_t*)ws; ws += (size_t)2048 * 4096 * 2;  // hidden fp16; later ab
  ushort_t* Qf16 = (ushort_t*)ws; ws += (size_t)2048 * 4096 * 2;  // Q proj out; later P1 (w/ KVf)
  float*    KVf  = (float*)ws;    ws += (size_t)2048 * 2048 * 4;  // KV proj out fp32
  ushort_t* vrow = (ushort_t*)ws; ws += (size_t)2048 * 1024 * 2;  // quantized V rows fp16
  ushort_t* kb   = (ushort_t*)ws; ws += (size_t)2048 * 1024 * 2;  // (B,KVH,S,D) fp16
  ushort_t* vb   = (ushort_t*)ws;                                 // (B,KVH,D,S) fp16

  ushort_t* Woh = Wall;                               // Wo fp16 (after QKV GEMM)
  ushort_t* qb  = Wall + (size_t)4096 * 4096;         // (B,NH,S,D), overlays Wk/Wv fp16
  ushort_t* ab  = hh;                                 // attn out (B,S,NH*D)
  float*    P1  = (float*)Qf16;                       // split-K partial, overlays Qf16+KVf

  // conversions to fp16
  cvt16<<<8192, 256, 0, stream>>>(hidden, hh, 2048 * 4096 / 4);
  cvt16<<<16384, 256, 0, stream>>>(Wq, Wall, 4096 * 4096 / 4);
  cvt16<<<4096, 256, 0, stream>>>(Wk, Wall + (size_t)4096 * 4096, 1024 * 4096 / 4);
  cvt16<<<4096, 256, 0, stream>>>(Wv, Wall + (size_t)5120 * 4096, 1024 * 4096 / 4);

  // fused QKV projection (256^2 tiles, 24x8 grid, 512 threads, 64 KiB LDS)
  gemm_qkv<<<dim3(24, 8), 512, 0, stream>>>(hh, Wall, Qf16, KVf);

  // fake-quant (exact order statistics)
  kquant<<<1024, 256, 0, stream>>>(KVf);
  vquant<<<2048, 256, 0, stream>>>(KVf, vrow);
  vtrans<<<dim3(16, 32), 256, 0, stream>>>(vrow, vb);

  // RoPE + layout (qb overlays dead Wk/Wv region)
  rope_q<<<16384, 256, 0, stream>>>(Qf16, pos, qb);
  rope_k<<<4096, 256, 0, stream>>>(KVf, pos, kb);

  // Wo conversion into Wall head (Wq fp16 dead)
  cvt16<<<16384, 256, 0, stream>>>(Wo, Woh, 4096 * 4096 / 4);

  // attention (work-balanced: 2 q-tiles per block, 18 K-iters each)
  attn_fwd<<<dim3(4, 64), 256, 0, stream>>>(qb, kb, vb, ab);

  // output projection, split-K=2 (z=0 -> outp, z=1 -> P1), then reduce
  gemm_o<<<dim3(16, 8, 2), 512, 0, stream>>>(ab, Woh, outp, P1);
  reduce2<<<8192, 256, 0, stream>>>(outp, P1, 2048 * 4096 / 4);
}